// Round 16
// baseline (519.191 us; speedup 1.0000x reference)
//
#include <hip/hip_runtime.h>

typedef unsigned short u16;
typedef unsigned int u32;
typedef unsigned long long u64;
typedef __attribute__((ext_vector_type(8))) short short8;
typedef __attribute__((ext_vector_type(4))) float f32x4;

#define DEV static __device__ __forceinline__

// DPP lane-permute within 16-lane rows (pure VALU, no LDS pipe)
#define DPPF(v, c) __int_as_float(__builtin_amdgcn_mov_dpp(__float_as_int(v), (c), 0xf, 0xf, true))

DEV u16 f2b(float f) {
  union { float f; u32 u; } a; a.f = f;
  u32 r = a.u + 0x7fffu + ((a.u >> 16) & 1u);
  return (u16)(r >> 16);
}

DEV f32x4 mfma16(short8 a, short8 b, f32x4 c) {
  return __builtin_amdgcn_mfma_f32_16x16x32_bf16(a, b, c, 0, 0, 0);
}

DEV void async16(const void* g, void* l) {
  __builtin_amdgcn_global_load_lds(
      (const __attribute__((address_space(1))) u32*)g,
      (__attribute__((address_space(3))) u32*)l, 16, 0, 0);
}

// ---------------- f32 -> bf16, three weight tensors in one launch (dst contig)
__global__ __launch_bounds__(256) void f2bf_multi(
    const float* __restrict__ s0, const float* __restrict__ s1,
    const float* __restrict__ s2, u16* __restrict__ dst) {
  const int stride = gridDim.x * 256;
  for (int i = blockIdx.x * 256 + threadIdx.x; i < 2097152; i += stride) {
    f32x4 v;
    if (i < 786432) v = ((const f32x4*)s0)[i];
    else if (i < 1048576) v = ((const f32x4*)s1)[i - 786432];
    else v = ((const f32x4*)s2)[i - 1048576];
    union { u64 q; u16 s[4]; } pk;
    pk.s[0] = f2b(v[0]); pk.s[1] = f2b(v[1]); pk.s[2] = f2b(v[2]); pk.s[3] = f2b(v[3]);
    ((u64*)dst)[i] = pk.q;
  }
}

// --------------------- keys = mu * softplus(sigma), kn_inv = 1/max(||k||,eps)
__global__ __launch_bounds__(256) void prep_keys(
    const float* __restrict__ mu, const float* __restrict__ sg,
    u16* __restrict__ wcat, float* __restrict__ kn) {
  __shared__ float s1[4];
  const int row = blockIdx.x, tid = threadIdx.x, lane = tid & 63, wave = tid >> 6;
  const f32x4 m = *(const f32x4*)(mu + (size_t)row * 1024 + tid * 4);
  const f32x4 s = *(const f32x4*)(sg + (size_t)row * 1024 + tid * 4);
  float q = 0.f;
  union { u64 q; u16 s[4]; } pkk, pkm;
  #pragma unroll
  for (int j = 0; j < 4; ++j) {
    const float sp = (s[j] > 20.f) ? s[j] : log1pf(__expf(s[j]));
    const float k = m[j] * sp;
    q += k * k;
    pkk.s[j] = f2b(k);
    pkm.s[j] = f2b(m[j]);
  }
  *(u64*)(wcat + (size_t)row * 1024 + tid * 4) = pkk.q;
  *(u64*)(wcat + (size_t)(4096 + row) * 1024 + tid * 4) = pkm.q;
  #pragma unroll
  for (int d = 1; d < 64; d <<= 1) q += __shfl_xor(q, d);
  if (lane == 0) s1[wave] = q;
  __syncthreads();
  if (tid == 0) kn[row] = 1.0f / fmaxf(sqrtf(s1[0] + s1[1] + s1[2] + s1[3]), 1e-8f);
}

// --------------- layernorm, wave-per-row (4 rows/block, no LDS, no barriers)
__global__ __launch_bounds__(256) void ln4_kernel(
    const float* __restrict__ x, const float* __restrict__ w,
    const float* __restrict__ b, u16* __restrict__ y, float* __restrict__ xn) {
  const int tid = threadIdx.x, lane = tid & 63, wave = tid >> 6;
  const int row = blockIdx.x * 4 + wave;
  const float* xr = x + (size_t)row * 1024;
  f32x4 xv[4];
  float s = 0.f, q = 0.f;
  #pragma unroll
  for (int j = 0; j < 4; ++j) {
    xv[j] = *(const f32x4*)(xr + j * 256 + lane * 4);
    #pragma unroll
    for (int u = 0; u < 4; ++u) { s += xv[j][u]; q += xv[j][u] * xv[j][u]; }
  }
  #pragma unroll
  for (int d = 1; d < 64; d <<= 1) { s += __shfl_xor(s, d); q += __shfl_xor(q, d); }
  const float mean = s * (1.f / 1024.f);
  const float inv = rsqrtf(q * (1.f / 1024.f) - mean * mean + 1e-5f);
  float qs = 0.f;
  #pragma unroll
  for (int j = 0; j < 4; ++j) {
    const f32x4 wv = *(const f32x4*)(w + j * 256 + lane * 4);
    const f32x4 bv = *(const f32x4*)(b + j * 256 + lane * 4);
    union { u64 q; u16 s[4]; } pk;
    #pragma unroll
    for (int u = 0; u < 4; ++u) {
      const float yv = (xv[j][u] - mean) * inv * wv[u] + bv[u];
      qs += yv * yv;
      pk.s[u] = f2b(yv);
    }
    *(u64*)(y + (size_t)row * 1024 + j * 256 + lane * 4) = pk.q;
  }
  if (xn) {
    #pragma unroll
    for (int d = 1; d < 64; d <<= 1) qs += __shfl_xor(qs, d);
    if (lane == 0) xn[row] = 1.0f / fmaxf(sqrtf(qs), 1e-8f);
  }
}

// ---------------------- GEMM C = A[M,K] * W[N,K]^T  (round-3 chassis, now with
// the v3 CONFLICT-FREE swizzle pair: staged slot j0 at row-pair rp holds
// (parity j0&1, colchunk (j0>>1)^(rp&3)); read laneoff inverts it.)
template<int MODE, int BM>
__global__ __launch_bounds__(512, 2) void gemm_bt(
    const u16* __restrict__ A, const u16* __restrict__ W,
    int M, int N, int K,
    const float* __restrict__ aux0, const float* __restrict__ aux1,
    float* __restrict__ fo0,
    u16* __restrict__ bo0, u16* __restrict__ bo1, u16* __restrict__ bo2) {
  constexpr int MF = BM / 32;
  constexpr int A_U16 = BM * 32;
  constexpr int STRIDE = A_U16 + 8192;
  constexpr int AISS = BM / 128;
  constexpr int LPT = AISS + 2;
  __shared__ __align__(16) u16 lds[3 * STRIDE];

  const int tid = threadIdx.x;
  const int lane = tid & 63, wave = tid >> 6;
  const int x = lane & 15, g = lane >> 4;
  const int wm = wave >> 2, wn = wave & 3;

  const int gx = N >> 8;
  const int nwg = gridDim.x;
  const int wg = ((int)blockIdx.x & 7) * (nwg >> 3) + ((int)blockIdx.x >> 3);
  const int by = wg / gx, bx = wg - by * gx;
  const int m0 = by * BM, n0 = bx * 256;

  const u16* srcA[AISS]; const u16* srcB[2];
  int dA[AISS], dB[2];
  #pragma unroll
  for (int i = 0; i < AISS; ++i) {
    const int rp = i * 64 + (tid >> 3);
    const int j0 = tid & 7;
    const int row = rp * 2 + (j0 & 1), col = (((j0 >> 1) ^ (rp & 3)) & 3) * 8;
    srcA[i] = A + (size_t)(m0 + row) * K + col;
    dA[i] = i * 4096 + tid * 8;
  }
  #pragma unroll
  for (int i = 0; i < 2; ++i) {
    const int rp = i * 64 + (tid >> 3);
    const int j0 = tid & 7;
    const int row = rp * 2 + (j0 & 1), col = (((j0 >> 1) ^ (rp & 3)) & 3) * 8;
    srcB[i] = W + (size_t)(n0 + row) * K + col;
    dB[i] = A_U16 + i * 4096 + tid * 8;
  }
  const int hq = x >> 1;
  const int lane_off = hq * 64 + (((2 * g + (x & 1)) ^ ((hq & 3) << 1)) * 8);
  const int aoff = wm * (BM / 4) * 64 + lane_off;
  const int boff = A_U16 + wn * 2048 + lane_off;

  f32x4 acc[MF][4];
  #pragma unroll
  for (int f = 0; f < MF; ++f)
    #pragma unroll
    for (int j = 0; j < 4; ++j) acc[f][j] = (f32x4){0.f, 0.f, 0.f, 0.f};

  const int NT = K >> 5;
  auto stage = [&](int t, int b) {
    u16* buf = lds + b * STRIDE;
    const size_t ko = (size_t)t * 32;
    #pragma unroll
    for (int i = 0; i < AISS; ++i) async16(srcA[i] + ko, buf + dA[i]);
    #pragma unroll
    for (int i = 0; i < 2; ++i) async16(srcB[i] + ko, buf + dB[i]);
  };
  stage(0, 0);
  stage(1, 1);
  int br = 0, bs = 2;
  for (int t = 0; t < NT; ++t) {
    if (t < NT - 1)
      asm volatile("s_waitcnt vmcnt(%0)\n\ts_barrier" :: "n"(LPT) : "memory");
    else
      asm volatile("s_waitcnt vmcnt(0)\n\ts_barrier" ::: "memory");
    const u16* bufr = lds + br * STRIDE;
    short8 bfr[4], af[MF];
    #pragma unroll
    for (int j = 0; j < 4; ++j) bfr[j] = *(const short8*)(bufr + boff + j * 512);
    #pragma unroll
    for (int f = 0; f < MF; ++f) af[f] = *(const short8*)(bufr + aoff + f * 512);
    if (t + 2 < NT) stage(t + 2, bs);
    __builtin_amdgcn_s_setprio(1);
    #pragma unroll
    for (int f = 0; f < MF; ++f)
      #pragma unroll
      for (int j = 0; j < 4; ++j) acc[f][j] = mfma16(af[f], bfr[j], acc[f][j]);
    __builtin_amdgcn_s_setprio(0);
    br = (br == 2) ? 0 : br + 1;
    bs = (bs == 2) ? 0 : bs + 1;
  }

  const int col_base = n0 + wn * 64;
  const int row_base = m0 + wm * (BM / 2);
  #pragma unroll
  for (int f = 0; f < MF; ++f)
    #pragma unroll
    for (int j = 0; j < 4; ++j)
      #pragma unroll
      for (int r = 0; r < 4; ++r) {
        const int row = row_base + f * 16 + g * 4 + r;
        const int col = col_base + j * 16 + x;
        float v = acc[f][j][r];
        if constexpr (MODE == 0) {
          v += aux0[col];
          const int part = col >> 10, cc = col & 1023;
          const int hh = cc >> 6, dd = cc & 63;
          const size_t idx = ((size_t)((row >> 10) * 16 + hh) * 1024 + (row & 1023)) * 64 + dd;
          if (part == 0) bo0[idx] = f2b(v * 0.125f);
          else if (part == 1) bo1[idx] = f2b(v);
          else bo2[idx] = f2b(v);
        } else if constexpr (MODE == 1) {
          fo0[(size_t)row * 1024 + col] = v + aux0[col] + aux1[(size_t)row * 1024 + col];
        } else {
          __builtin_nontemporal_store(
              v + aux0[col] + aux1[(size_t)row * 1024 + col],
              &fo0[(size_t)row * 1024 + col]);
        }
      }
}

// ---------------- moie GEMM v5c: v5b chassis (2 blocks/CU, 42% occ) + the v3
// CONFLICT-FREE swizzle pair (measured 0 conflicts in rounds 6-13).
// B rows = keys/mu interleaved in 32-row chunks; register-local fused epilogue.
__global__ __launch_bounds__(512, 4) void moie_gemm(
    const u16* __restrict__ A, const u16* __restrict__ W,
    const float* __restrict__ xni, const float* __restrict__ kni,
    const float* __restrict__ mub, const float* __restrict__ gate,
    float* __restrict__ oscore, float* __restrict__ omask,
    u16* __restrict__ oact) {
  constexpr int STRIDE = 12288;   // A 4096 | B 8192 u16
  __shared__ __align__(16) u16 lds[3 * STRIDE];
  const int tid = threadIdx.x;
  const int lane = tid & 63, wave = tid >> 6;
  const int x = lane & 15, g = lane >> 4;
  const int wm = wave >> 2, wn = wave & 3;

  // 2048 blocks = 64 by x 32 bx; XCD-panel decode: 8 by-rows per XCD, bx slow
  const int bid = (int)blockIdx.x;
  const int local = bid >> 3;
  const int by = (bid & 7) * 8 + (local & 7);
  const int bx = local >> 3;
  const int m0 = by * 128, n0 = bx * 128;

  // staging: v3 conflict-free inverse swizzle
  const u16* srcA;
  const u16* srcB[2];
  {
    const int rp = tid >> 3, j0 = tid & 7;
    const int row = rp * 2 + (j0 & 1), col = (((j0 >> 1) ^ (rp & 3)) & 3) * 8;
    srcA = A + (size_t)(m0 + row) * 1024 + col;
  }
  #pragma unroll
  for (int i = 0; i < 2; ++i) {
    const int rp = i * 64 + (tid >> 3), j0 = tid & 7;
    const int rb = rp * 2 + (j0 & 1), col = (((j0 >> 1) ^ (rp & 3)) & 3) * 8;
    const u16* base = (rb & 32) ? (W + (size_t)4096 * 1024) : W;
    srcB[i] = base + (size_t)(n0 + ((rb >> 6) << 5) + (rb & 31)) * 1024 + col;
  }
  const int dB0 = 4096 + tid * 8, dB1 = 8192 + tid * 8;
  const int hq = x >> 1;
  const int lane_off = hq * 64 + (((2 * g + (x & 1)) ^ ((hq & 3) << 1)) * 8);
  const int aoff = wm * 2048 + lane_off;
  const int boff = 4096 + wn * 2048 + lane_off;

  f32x4 acc[4][4];
  #pragma unroll
  for (int f = 0; f < 4; ++f)
    #pragma unroll
    for (int j = 0; j < 4; ++j) acc[f][j] = (f32x4){0.f, 0.f, 0.f, 0.f};

  constexpr int NT = 32;
  auto stage = [&](int t, int b) {
    u16* buf = lds + b * STRIDE;
    const size_t ko = (size_t)t * 32;
    async16(srcA + ko, buf + tid * 8);
    async16(srcB[0] + ko, buf + dB0);
    async16(srcB[1] + ko, buf + dB1);
  };
  stage(0, 0);
  stage(1, 1);
  int br = 0, bs = 2;
  for (int t = 0; t < NT; ++t) {
    if (t < NT - 1)
      asm volatile("s_waitcnt vmcnt(3)\n\ts_barrier" ::: "memory");
    else
      asm volatile("s_waitcnt vmcnt(0)\n\ts_barrier" ::: "memory");
    const u16* bufr = lds + br * STRIDE;
    short8 bfr[4], af[4];
    #pragma unroll
    for (int j = 0; j < 4; ++j) bfr[j] = *(const short8*)(bufr + boff + j * 512);
    #pragma unroll
    for (int f = 0; f < 4; ++f) af[f] = *(const short8*)(bufr + aoff + f * 512);
    if (t + 2 < NT) stage(t + 2, bs);
    __builtin_amdgcn_s_setprio(1);
    #pragma unroll
    for (int f = 0; f < 4; ++f)
      #pragma unroll
      for (int j = 0; j < 4; ++j) acc[f][j] = mfma16(af[f], bfr[j], acc[f][j]);
    __builtin_amdgcn_s_setprio(0);
    br = (br == 2) ? 0 : br + 1;
    bs = (bs == 2) ? 0 : bs + 1;
  }

  // register-local fused epilogue: acc[f][0..1]=dots, acc[f][2..3]=comp
  #pragma unroll
  for (int f = 0; f < 4; ++f) {
    const int row = m0 + wm * 64 + f * 16 + g * 4;
    const f32x4 xv = *(const f32x4*)(xni + row);
    #pragma unroll
    for (int jj = 0; jj < 2; ++jj) {
      const int gcol = n0 + wn * 32 + jj * 16 + x;
      const float kv = kni[gcol], gt = gate[gcol], mb = mub[gcol];
      #pragma unroll
      for (int r = 0; r < 4; ++r) {
        const float s = acc[f][jj][r] * xv[r] * kv;
        const float comp = acc[f][jj + 2][r] + mb;
        const float mk = comp * fmaxf(s - gt, 0.f);
        oscore[(size_t)(row + r) * 4096 + gcol] = s;
        omask[(size_t)(row + r) * 4096 + gcol] = mk;
        oact[(size_t)(row + r) * 4096 + gcol] = f2b(mk / (1.f + __expf(-mk)));
      }
    }
  }
}

// ---------------------------------------- V transpose: v[bh][s][d] -> vt[bh][d][s]
__global__ __launch_bounds__(256) void vtrans(const u16* __restrict__ v,
                                              u16* __restrict__ vt) {
  __shared__ u16 tl[64 * 66];
  const int bh = blockIdx.y, s0 = blockIdx.x * 64;
  const int tid = threadIdx.x;
  const int r8 = tid >> 3, c8 = tid & 7;
  #pragma unroll
  for (int p = 0; p < 2; ++p) {
    const int row = r8 + p * 32;
    *(short8*)&tl[row * 66 + c8 * 8] =
        *(const short8*)&v[((size_t)bh * 1024 + s0 + row) * 64 + c8 * 8];
  }
  __syncthreads();
  #pragma unroll
  for (int p = 0; p < 2; ++p) {
    const int d = r8 + p * 32;
    union { short8 v; u16 s[8]; } pk;
    #pragma unroll
    for (int j = 0; j < 8; ++j) pk.s[j] = tl[(c8 * 8 + j) * 66 + d];
    *(short8*)&vt[((size_t)bh * 64 + d) * 1024 + s0 + c8 * 8] = pk.v;
  }
}

// ------------------- flash attention v3 (round-13 best: DPP softmax)
__global__ __launch_bounds__(256) void attn_kernel(
    const u16* __restrict__ Q, const u16* __restrict__ Kg,
    const u16* __restrict__ Vtg, u16* __restrict__ O) {
  __shared__ __align__(16) u16 Kb[2][4096];
  __shared__ __align__(16) u16 Vb[2][4096];
  __shared__ __align__(16) u16 Pl[4][1024];
  const int bh = blockIdx.x;
  const int qt = blockIdx.y;
  const int tid = threadIdx.x, lane = tid & 63, wave = tid >> 6;
  const int x = lane & 15, g = lane >> 4;
  const u16* Qb = Q + (size_t)bh * 1024 * 64;
  const int qbase = qt * 64 + wave * 16;
  const short8 qf0 = *(const short8*)&Qb[(qbase + x) * 64 + g * 8];
  const short8 qf1 = *(const short8*)&Qb[(qbase + x) * 64 + 32 + g * 8];

  const int rp = tid >> 3, j0 = tid & 7;
  const int prow = rp * 2 + (j0 & 1);
  const int pcol = (((j0 >> 1) ^ (rp & 3)) & 3) * 8;
  const u16* srcK = Kg + (size_t)bh * 65536 + (size_t)prow * 64 + pcol;
  const u16* srcV = Vtg + (size_t)(bh * 64 + prow) * 1024 + pcol;
  const int dst0 = tid * 8;
  const int h = x >> 1, pq = x & 1;
  const int laneoff = h * 64 + (((2 * g + pq) ^ ((h & 3) << 1)) * 8);

  float mrun[4], lrun[4];
  f32x4 oacc[4];
  #pragma unroll
  for (int r = 0; r < 4; ++r) { mrun[r] = -1e30f; lrun[r] = 0.f; }
  #pragma unroll
  for (int d = 0; d < 4; ++d) oacc[d] = (f32x4){0.f, 0.f, 0.f, 0.f};

  auto stage = [&](int t) {
    u16* kd = Kb[t & 1] + dst0;
    u16* vd = Vb[t & 1] + dst0;
    const u16* ks = srcK + t * 4096;
    const u16* vs = srcV + t * 64;
    async16(ks, kd);        async16(ks + 32, kd + 2048);
    async16(vs, vd);        async16(vs + 32, vd + 2048);
  };
  stage(0);
  asm volatile("s_waitcnt vmcnt(0)\n\ts_barrier" ::: "memory");

  for (int t = 0; t <= qt; ++t) {
    const u16* kb = Kb[t & 1];
    const u16* vb = Vb[t & 1];
    if (t < qt) stage(t + 1);

    float sc[4][4];
    #pragma unroll
    for (int nb = 0; nb < 4; ++nb) {
      f32x4 a = (f32x4){0.f, 0.f, 0.f, 0.f};
      const short8 kf0 = *(const short8*)(kb + nb * 512 + laneoff);
      const short8 kf1 = *(const short8*)(kb + 2048 + nb * 512 + laneoff);
      a = mfma16(qf0, kf0, a);
      a = mfma16(qf1, kf1, a);
      #pragma unroll
      for (int r = 0; r < 4; ++r) sc[nb][r] = a[r];
    }
    if (t == qt) {
      #pragma unroll
      for (int nb = 0; nb < 4; ++nb)
        #pragma unroll
        for (int r = 0; r < 4; ++r)
          if (t * 64 + nb * 16 + x > qbase + g * 4 + r) sc[nb][r] = -1e30f;
    }
    float mnew[4], psum[4], scl[4];
    #pragma unroll
    for (int r = 0; r < 4; ++r) {
      float mx = fmaxf(fmaxf(sc[0][r], sc[1][r]), fmaxf(sc[2][r], sc[3][r]));
      mx = fmaxf(mx, DPPF(mx, 0xB1));
      mx = fmaxf(mx, DPPF(mx, 0x4E));
      mx = fmaxf(mx, DPPF(mx, 0x124));
      mx = fmaxf(mx, DPPF(mx, 0x128));
      mnew[r] = fmaxf(mrun[r], mx);
      scl[r] = __expf(mrun[r] - mnew[r]);
      mrun[r] = mnew[r];
      psum[r] = 0.f;
    }
    float p[4][4];
    #pragma unroll
    for (int nb = 0; nb < 4; ++nb)
      #pragma unroll
      for (int r = 0; r < 4; ++r) {
        p[nb][r] = __expf(sc[nb][r] - mnew[r]);
        psum[r] += p[nb][r];
      }
    #pragma unroll
    for (int r = 0; r < 4; ++r) {
      psum[r] += DPPF(psum[r], 0xB1);
      psum[r] += DPPF(psum[r], 0x4E);
      psum[r] += DPPF(psum[r], 0x124);
      psum[r] += DPPF(psum[r], 0x128);
      lrun[r] = lrun[r] * scl[r] + psum[r];
      #pragma unroll
      for (int db = 0; db < 4; ++db) oacc[db][r] *= scl[r];
    }
    u16* Pw = Pl[wave];
    #pragma unroll
    for (int nb = 0; nb < 4; ++nb) {
      const int half = nb >> 1;
      #pragma unroll
      for (int r = 0; r < 4; ++r) {
        const int qr = g * 4 + r;
        const int col5 = (nb & 1) * 16 + x;
        const int c8 = col5 >> 3, c7 = col5 & 7;
        const int rq = qr >> 1;
        const int jq = (qr & 1) | ((c8 ^ (rq & 3)) << 1);
        Pw[half * 512 + rq * 64 + jq * 8 + c7] = f2b(p[nb][r]);
      }
    }
    const short8 pf0 = *(const short8*)(Pw + laneoff);
    const short8 pf1 = *(const short8*)(Pw + 512 + laneoff);
    #pragma unroll
    for (int db = 0; db < 4; ++db) {
      const short8 vf0 = *(const short8*)(vb + db * 512 + laneoff);
      const short8 vf1 = *(const short8*)(vb + 2048 + db * 512 + laneoff);
      oacc[db] = mfma16(pf0, vf0, oacc[db]);
      oacc[db] = mfma16(pf1, vf1, oacc[db]);
    }
    if (t < qt)
      asm volatile("s_waitcnt vmcnt(0)\n\ts_barrier" ::: "memory");
  }
  const int b = bh >> 4, hh = bh & 15;
  #pragma unroll
  for (int db = 0; db < 4; ++db)
    #pragma unroll
    for (int r = 0; r < 4; ++r) {
      const int qrow = qbase + g * 4 + r;
      O[((size_t)(b * 1024 + qrow)) * 1024 + hh * 64 + db * 16 + x] = f2b(oacc[db][r] / lrun[r]);
    }
}

// ---------------------------------------------------------------------- launch
extern "C" void kernel_launch(void* const* d_in, const int* in_sizes, int n_in,
                              void* d_out, int out_size, void* d_ws, size_t ws_size,
                              hipStream_t stream) {
  const float* x    = (const float*)d_in[0];
  const float* ln1w = (const float*)d_in[1];
  const float* ln1b = (const float*)d_in[2];
  const float* wip  = (const float*)d_in[3];
  const float* bip  = (const float*)d_in[4];
  const float* wop  = (const float*)d_in[5];
  const float* bop  = (const float*)d_in[6];
  const float* ln2w = (const float*)d_in[7];
  const float* ln2b = (const float*)d_in[8];
  const float* muw  = (const float*)d_in[9];
  const float* sgw  = (const float*)d_in[10];
  const float* gate = (const float*)d_in[11];
  const float* mub  = (const float*)d_in[12];
  const float* wf2  = (const float*)d_in[13];
  const float* bf2  = (const float*)d_in[14];

  float* out_x = (float*)d_out;
  float* out_scores = out_x + (size_t)8192 * 1024;
  float* out_masked = out_scores + (size_t)8192 * 4096;

  char* ws = (char*)d_ws;
  size_t off = 0;
  auto alloc = [&](size_t n) { char* p = ws + off; off += (n + 255) & ~(size_t)255; return p; };
  u16* h_bf    = (u16*)alloc((size_t)8192 * 1024 * 2);
  u16* q_bf    = (u16*)alloc((size_t)8192 * 1024 * 2);
  u16* k_bf    = (u16*)alloc((size_t)8192 * 1024 * 2);
  u16* v_bf    = (u16*)alloc((size_t)8192 * 1024 * 2);
  u16* vt_bf   = (u16*)alloc((size_t)8192 * 1024 * 2);
  u16* o_bf    = (u16*)alloc((size_t)8192 * 1024 * 2);
  float* x_res = (float*)alloc((size_t)8192 * 1024 * 4);
  u16* xr_bf   = (u16*)alloc((size_t)8192 * 1024 * 2);
  float* xn    = (float*)alloc((size_t)8192 * 4);
  float* kn    = (float*)alloc((size_t)4096 * 4);
  u16* wcat    = (u16*)alloc((size_t)8192 * 1024 * 2);
  u16* wip_b   = (u16*)alloc((size_t)3072 * 1024 * 2);
  u16* wop_b   = (u16*)alloc((size_t)1024 * 1024 * 2);
  u16* wf2_b   = (u16*)alloc((size_t)1024 * 4096 * 2);
  u16* act_bf  = (u16*)alloc((size_t)8192 * 4096 * 2);

  f2bf_multi<<<2048, 256, 0, stream>>>(wip, wop, wf2, wip_b);
  prep_keys<<<4096, 256, 0, stream>>>(muw, sgw, wcat, kn);
  ln4_kernel<<<2048, 256, 0, stream>>>(x, ln1w, ln1b, h_bf, nullptr);
  gemm_bt<0, 128><<<768, 512, 0, stream>>>(h_bf, wip_b, 8192, 3072, 1024,
      bip, nullptr, nullptr, q_bf, k_bf, v_bf);
  vtrans<<<dim3(16, 128), 256, 0, stream>>>(v_bf, vt_bf);
  attn_kernel<<<dim3(128, 16), 256, 0, stream>>>(q_bf, k_bf, vt_bf, o_bf);
  gemm_bt<1, 128><<<256, 512, 0, stream>>>(o_bf, wop_b, 8192, 1024, 1024,
      bop, x, x_res, nullptr, nullptr, nullptr);
  ln4_kernel<<<2048, 256, 0, stream>>>(x_res, ln2w, ln2b, xr_bf, xn);
  moie_gemm<<<2048, 512, 0, stream>>>(xr_bf, wcat, xn, kn, mub, gate,
      out_scores, out_masked, act_bf);
  gemm_bt<3, 128><<<256, 512, 0, stream>>>(act_bf, wf2_b, 8192, 1024, 4096,
      bf2, x_res, out_x, nullptr, nullptr, nullptr);
}

// Round 17
// 501.060 us; speedup vs baseline: 1.0362x; 1.0362x over previous
//
#include <hip/hip_runtime.h>

typedef unsigned short u16;
typedef unsigned int u32;
typedef unsigned long long u64;
typedef __attribute__((ext_vector_type(8))) short short8;
typedef __attribute__((ext_vector_type(4))) float f32x4;

#define DEV static __device__ __forceinline__

// DPP lane-permute within 16-lane rows (pure VALU, no LDS pipe)
#define DPPF(v, c) __int_as_float(__builtin_amdgcn_mov_dpp(__float_as_int(v), (c), 0xf, 0xf, true))

DEV u16 f2b(float f) {
  union { float f; u32 u; } a; a.f = f;
  u32 r = a.u + 0x7fffu + ((a.u >> 16) & 1u);
  return (u16)(r >> 16);
}

DEV f32x4 mfma16(short8 a, short8 b, f32x4 c) {
  return __builtin_amdgcn_mfma_f32_16x16x32_bf16(a, b, c, 0, 0, 0);
}

DEV void async16(const void* g, void* l) {
  __builtin_amdgcn_global_load_lds(
      (const __attribute__((address_space(1))) u32*)g,
      (__attribute__((address_space(3))) u32*)l, 16, 0, 0);
}

// ---------------- f32 -> bf16, three weight tensors in one launch (dst contig)
__global__ __launch_bounds__(256) void f2bf_multi(
    const float* __restrict__ s0, const float* __restrict__ s1,
    const float* __restrict__ s2, u16* __restrict__ dst) {
  const int stride = gridDim.x * 256;
  // segments (in f32x4 units): wip 786432 | wop 262144 | wf2 1048576
  for (int i = blockIdx.x * 256 + threadIdx.x; i < 2097152; i += stride) {
    f32x4 v;
    if (i < 786432) v = ((const f32x4*)s0)[i];
    else if (i < 1048576) v = ((const f32x4*)s1)[i - 786432];
    else v = ((const f32x4*)s2)[i - 1048576];
    union { u64 q; u16 s[4]; } pk;
    pk.s[0] = f2b(v[0]); pk.s[1] = f2b(v[1]); pk.s[2] = f2b(v[2]); pk.s[3] = f2b(v[3]);
    ((u64*)dst)[i] = pk.q;
  }
}

// --------------------- keys = mu * softplus(sigma), kn_inv = 1/max(||k||,eps)
__global__ __launch_bounds__(256) void prep_keys(
    const float* __restrict__ mu, const float* __restrict__ sg,
    u16* __restrict__ wcat, float* __restrict__ kn) {
  __shared__ float s1[4];
  const int row = blockIdx.x, tid = threadIdx.x, lane = tid & 63, wave = tid >> 6;
  const f32x4 m = *(const f32x4*)(mu + (size_t)row * 1024 + tid * 4);
  const f32x4 s = *(const f32x4*)(sg + (size_t)row * 1024 + tid * 4);
  float q = 0.f;
  union { u64 q; u16 s[4]; } pkk, pkm;
  #pragma unroll
  for (int j = 0; j < 4; ++j) {
    const float sp = (s[j] > 20.f) ? s[j] : log1pf(__expf(s[j]));
    const float k = m[j] * sp;
    q += k * k;
    pkk.s[j] = f2b(k);
    pkm.s[j] = f2b(m[j]);
  }
  *(u64*)(wcat + (size_t)row * 1024 + tid * 4) = pkk.q;
  *(u64*)(wcat + (size_t)(4096 + row) * 1024 + tid * 4) = pkm.q;
  #pragma unroll
  for (int d = 1; d < 64; d <<= 1) q += __shfl_xor(q, d);
  if (lane == 0) s1[wave] = q;
  __syncthreads();
  if (tid == 0) kn[row] = 1.0f / fmaxf(sqrtf(s1[0] + s1[1] + s1[2] + s1[3]), 1e-8f);
}

// --------------- layernorm, wave-per-row (4 rows/block, no LDS, no barriers)
__global__ __launch_bounds__(256) void ln4_kernel(
    const float* __restrict__ x, const float* __restrict__ w,
    const float* __restrict__ b, u16* __restrict__ y, float* __restrict__ xn) {
  const int tid = threadIdx.x, lane = tid & 63, wave = tid >> 6;
  const int row = blockIdx.x * 4 + wave;
  const float* xr = x + (size_t)row * 1024;
  f32x4 xv[4];
  float s = 0.f, q = 0.f;
  #pragma unroll
  for (int j = 0; j < 4; ++j) {
    xv[j] = *(const f32x4*)(xr + j * 256 + lane * 4);
    #pragma unroll
    for (int u = 0; u < 4; ++u) { s += xv[j][u]; q += xv[j][u] * xv[j][u]; }
  }
  #pragma unroll
  for (int d = 1; d < 64; d <<= 1) { s += __shfl_xor(s, d); q += __shfl_xor(q, d); }
  const float mean = s * (1.f / 1024.f);
  const float inv = rsqrtf(q * (1.f / 1024.f) - mean * mean + 1e-5f);
  float qs = 0.f;
  #pragma unroll
  for (int j = 0; j < 4; ++j) {
    const f32x4 wv = *(const f32x4*)(w + j * 256 + lane * 4);
    const f32x4 bv = *(const f32x4*)(b + j * 256 + lane * 4);
    union { u64 q; u16 s[4]; } pk;
    #pragma unroll
    for (int u = 0; u < 4; ++u) {
      const float yv = (xv[j][u] - mean) * inv * wv[u] + bv[u];
      qs += yv * yv;
      pk.s[u] = f2b(yv);
    }
    *(u64*)(y + (size_t)row * 1024 + j * 256 + lane * 4) = pk.q;
  }
  if (xn) {
    #pragma unroll
    for (int d = 1; d < 64; d <<= 1) qs += __shfl_xor(qs, d);
    if (lane == 0) xn[row] = 1.0f / fmaxf(sqrtf(qs), 1e-8f);
  }
}

// ---------------------- GEMM C = A[M,K] * W[N,K]^T  (round-3 proven template)
template<int MODE, int BM>
__global__ __launch_bounds__(512, 2) void gemm_bt(
    const u16* __restrict__ A, const u16* __restrict__ W,
    int M, int N, int K,
    const float* __restrict__ aux0, const float* __restrict__ aux1,
    float* __restrict__ fo0,
    u16* __restrict__ bo0, u16* __restrict__ bo1, u16* __restrict__ bo2) {
  constexpr int MF = BM / 32;
  constexpr int A_U16 = BM * 32;
  constexpr int STRIDE = A_U16 + 8192;
  constexpr int AISS = BM / 128;
  constexpr int LPT = AISS + 2;
  __shared__ __align__(16) u16 lds[3 * STRIDE];

  const int tid = threadIdx.x;
  const int lane = tid & 63, wave = tid >> 6;
  const int x = lane & 15, g = lane >> 4;
  const int wm = wave >> 2, wn = wave & 3;

  const int gx = N >> 8;
  const int nwg = gridDim.x;
  const int wg = ((int)blockIdx.x & 7) * (nwg >> 3) + ((int)blockIdx.x >> 3);
  const int by = wg / gx, bx = wg - by * gx;
  const int m0 = by * BM, n0 = bx * 256;

  const u16* srcA[AISS]; const u16* srcB[2];
  int dA[AISS], dB[2];
  #pragma unroll
  for (int i = 0; i < AISS; ++i) {
    const int rp = i * 64 + (tid >> 3);
    const int pre = (tid & 7) ^ (rp & 7);
    const int row = rp * 2 + (pre & 1), col = (pre >> 1) * 8;
    srcA[i] = A + (size_t)(m0 + row) * K + col;
    dA[i] = i * 4096 + tid * 8;
  }
  #pragma unroll
  for (int i = 0; i < 2; ++i) {
    const int rp = i * 64 + (tid >> 3);
    const int pre = (tid & 7) ^ (rp & 7);
    const int row = rp * 2 + (pre & 1), col = (pre >> 1) * 8;
    srcB[i] = W + (size_t)(n0 + row) * K + col;
    dB[i] = A_U16 + i * 4096 + tid * 8;
  }
  const int lane_off = (x >> 1) * 64 + (((2 * g + (x & 1)) ^ (x >> 1)) * 8);
  const int aoff = wm * (BM / 4) * 64 + lane_off;
  const int boff = A_U16 + wn * 2048 + lane_off;

  f32x4 acc[MF][4];
  #pragma unroll
  for (int f = 0; f < MF; ++f)
    #pragma unroll
    for (int j = 0; j < 4; ++j) acc[f][j] = (f32x4){0.f, 0.f, 0.f, 0.f};

  const int NT = K >> 5;
  auto stage = [&](int t, int b) {
    u16* buf = lds + b * STRIDE;
    const size_t ko = (size_t)t * 32;
    #pragma unroll
    for (int i = 0; i < AISS; ++i) async16(srcA[i] + ko, buf + dA[i]);
    #pragma unroll
    for (int i = 0; i < 2; ++i) async16(srcB[i] + ko, buf + dB[i]);
  };
  stage(0, 0);
  stage(1, 1);
  int br = 0, bs = 2;
  for (int t = 0; t < NT; ++t) {
    if (t < NT - 1)
      asm volatile("s_waitcnt vmcnt(%0)\n\ts_barrier" :: "n"(LPT) : "memory");
    else
      asm volatile("s_waitcnt vmcnt(0)\n\ts_barrier" ::: "memory");
    const u16* bufr = lds + br * STRIDE;
    short8 bfr[4], af[MF];
    #pragma unroll
    for (int j = 0; j < 4; ++j) bfr[j] = *(const short8*)(bufr + boff + j * 512);
    #pragma unroll
    for (int f = 0; f < MF; ++f) af[f] = *(const short8*)(bufr + aoff + f * 512);
    if (t + 2 < NT) stage(t + 2, bs);
    __builtin_amdgcn_s_setprio(1);
    #pragma unroll
    for (int f = 0; f < MF; ++f)
      #pragma unroll
      for (int j = 0; j < 4; ++j) acc[f][j] = mfma16(af[f], bfr[j], acc[f][j]);
    __builtin_amdgcn_s_setprio(0);
    br = (br == 2) ? 0 : br + 1;
    bs = (bs == 2) ? 0 : bs + 1;
  }

  const int col_base = n0 + wn * 64;
  const int row_base = m0 + wm * (BM / 2);
  #pragma unroll
  for (int f = 0; f < MF; ++f)
    #pragma unroll
    for (int j = 0; j < 4; ++j)
      #pragma unroll
      for (int r = 0; r < 4; ++r) {
        const int row = row_base + f * 16 + g * 4 + r;
        const int col = col_base + j * 16 + x;
        float v = acc[f][j][r];
        if constexpr (MODE == 0) {
          v += aux0[col];
          const int part = col >> 10, cc = col & 1023;
          const int hh = cc >> 6, dd = cc & 63;
          const size_t idx = ((size_t)((row >> 10) * 16 + hh) * 1024 + (row & 1023)) * 64 + dd;
          if (part == 0) bo0[idx] = f2b(v * 0.125f);
          else if (part == 1) bo1[idx] = f2b(v);
          else bo2[idx] = f2b(v);
        } else if constexpr (MODE == 1) {
          fo0[(size_t)row * 1024 + col] = v + aux0[col] + aux1[(size_t)row * 1024 + col];
        } else {
          // ffn2 out_x: never re-read -> non-temporal
          __builtin_nontemporal_store(
              v + aux0[col] + aux1[(size_t)row * 1024 + col],
              &fo0[(size_t)row * 1024 + col]);
        }
      }
}

// ---------------- moie GEMM v3 (round-10 best: BK=32, 4-deep buffers, depth-3
// prefetch, ONE vmcnt(8)+barrier per K-tile, register-local fused epilogue)
__global__ __launch_bounds__(512, 2) void moie_gemm(
    const u16* __restrict__ A, const u16* __restrict__ W,
    const float* __restrict__ xni, const float* __restrict__ kni,
    const float* __restrict__ mub, const float* __restrict__ gate,
    float* __restrict__ oscore, float* __restrict__ omask,
    u16* __restrict__ oact) {
  __shared__ __align__(16) u16 lds[4 * 16384];
  const int tid = threadIdx.x;
  const int lane = tid & 63, wave = tid >> 6;
  const int x = lane & 15, g = lane >> 4, h = x >> 1, pp = x & 1;
  const int wm = wave >> 2, wn = wave & 3;

  const int bid = (int)blockIdx.x;
  const int local = bid >> 3;
  const int by = (bid & 7) * 4 + (local & 3);
  const int bx = local >> 2;
  const int m0 = by * 256, n0 = bx * 128;

  const int rp0 = tid >> 3, j0 = tid & 7;
  const int prow = rp0 * 2 + (j0 & 1);
  const int pcol = (((j0 >> 1) ^ (rp0 & 3)) & 3) * 8;
  const u16* Asrc[2]; const u16* Bsrc[2];
  Asrc[0] = A + (size_t)(m0 + prow) * 1024 + pcol;
  Asrc[1] = A + (size_t)(m0 + 128 + prow) * 1024 + pcol;
  #pragma unroll
  for (int c = 0; c < 2; ++c) {
    const int rb = c * 128 + prow;
    const u16* base = (rb & 32) ? (W + (size_t)4096 * 1024) : W;
    Bsrc[c] = base + (size_t)(n0 + ((rb >> 6) << 5) + (rb & 31)) * 1024 + pcol;
  }
  const int dst0 = tid * 8;
  const int laneoff = h * 64 + (((2 * g + pp) ^ ((h & 3) << 1)) * 8);

  f32x4 acc[8][4];
  #pragma unroll
  for (int i = 0; i < 8; ++i)
    #pragma unroll
    for (int j = 0; j < 4; ++j) acc[i][j] = (f32x4){0.f, 0.f, 0.f, 0.f};

  auto stageA = [&](int t) {
    u16* dst = lds + (t & 3) * 16384 + dst0;
    const int ko = t * 32;
    async16(Asrc[0] + ko, dst);
    async16(Asrc[1] + ko, dst + 4096);
  };
  auto stageB = [&](int t) {
    u16* dst = lds + (t & 3) * 16384 + 8192 + dst0;
    const int ko = t * 32;
    async16(Bsrc[0] + ko, dst);
    async16(Bsrc[1] + ko, dst + 4096);
  };

  stageA(0); stageB(0); stageA(1); stageB(1); stageA(2); stageB(2);
  asm volatile("s_waitcnt vmcnt(8)\n\ts_barrier" ::: "memory");

  constexpr int NT = 32;
  for (int t = 0; t < NT; ++t) {
    const u16* bufA = lds + (t & 3) * 16384;
    const u16* bufB = bufA + 8192;
    short8 bf[4], af[8];
    #pragma unroll
    for (int j = 0; j < 4; ++j)
      bf[j] = *(const short8*)(bufB + wn * 2048 + j * 512 + laneoff);
    #pragma unroll
    for (int f = 0; f < 8; ++f)
      af[f] = *(const short8*)(bufA + wm * 4096 + f * 512 + laneoff);
    if (t + 3 < NT) { stageB(t + 3); stageA(t + 3); }
    __builtin_amdgcn_s_setprio(1);
    #pragma unroll
    for (int f = 0; f < 8; ++f)
      #pragma unroll
      for (int j = 0; j < 4; ++j) acc[f][j] = mfma16(af[f], bf[j], acc[f][j]);
    __builtin_amdgcn_s_setprio(0);
    if (t <= NT - 4)
      asm volatile("s_waitcnt vmcnt(8)\n\ts_barrier" ::: "memory");
    else if (t == NT - 3)
      asm volatile("s_waitcnt vmcnt(4)\n\ts_barrier" ::: "memory");
    else if (t == NT - 2)
      asm volatile("s_waitcnt vmcnt(0)\n\ts_barrier" ::: "memory");
  }

  #pragma unroll
  for (int i = 0; i < 8; ++i) {
    const int row = m0 + wm * 128 + i * 16 + g * 4;
    const f32x4 xv = *(const f32x4*)(xni + row);
    #pragma unroll
    for (int jj = 0; jj < 2; ++jj) {
      const int gcol = n0 + wn * 32 + jj * 16 + x;
      const float kv = kni[gcol], gt = gate[gcol], mb = mub[gcol];
      #pragma unroll
      for (int r = 0; r < 4; ++r) {
        const float s = acc[i][jj][r] * xv[r] * kv;
        const float comp = acc[i][jj + 2][r] + mb;
        const float mk = comp * fmaxf(s - gt, 0.f);
        oscore[(size_t)(row + r) * 4096 + gcol] = s;
        omask[(size_t)(row + r) * 4096 + gcol] = mk;
        oact[(size_t)(row + r) * 4096 + gcol] = f2b(mk / (1.f + __expf(-mk)));
      }
    }
  }
}

// ---------------------------------------- V transpose: v[bh][s][d] -> vt[bh][d][s]
__global__ __launch_bounds__(256) void vtrans(const u16* __restrict__ v,
                                              u16* __restrict__ vt) {
  __shared__ u16 tl[64 * 66];
  const int bh = blockIdx.y, s0 = blockIdx.x * 64;
  const int tid = threadIdx.x;
  const int r8 = tid >> 3, c8 = tid & 7;
  #pragma unroll
  for (int p = 0; p < 2; ++p) {
    const int row = r8 + p * 32;
    *(short8*)&tl[row * 66 + c8 * 8] =
        *(const short8*)&v[((size_t)bh * 1024 + s0 + row) * 64 + c8 * 8];
  }
  __syncthreads();
  #pragma unroll
  for (int p = 0; p < 2; ++p) {
    const int d = r8 + p * 32;
    union { short8 v; u16 s[8]; } pk;
    #pragma unroll
    for (int j = 0; j < 8; ++j) pk.s[j] = tl[(c8 * 8 + j) * 66 + d];
    *(short8*)&vt[((size_t)bh * 64 + d) * 1024 + s0 + c8 * 8] = pk.v;
  }
}

// ------------------- flash attention v3: swizzled async16 staging, dbuf K/V,
// conflict-free frag reads, V pre-transposed globally, DPP softmax reductions.
__global__ __launch_bounds__(256) void attn_kernel(
    const u16* __restrict__ Q, const u16* __restrict__ Kg,
    const u16* __restrict__ Vtg, u16* __restrict__ O) {
  __shared__ __align__(16) u16 Kb[2][4096];
  __shared__ __align__(16) u16 Vb[2][4096];
  __shared__ __align__(16) u16 Pl[4][1024];
  const int bh = blockIdx.x;
  const int qt = blockIdx.y;
  const int tid = threadIdx.x, lane = tid & 63, wave = tid >> 6;
  const int x = lane & 15, g = lane >> 4;
  const u16* Qb = Q + (size_t)bh * 1024 * 64;
  const int qbase = qt * 64 + wave * 16;
  const short8 qf0 = *(const short8*)&Qb[(qbase + x) * 64 + g * 8];
  const short8 qf1 = *(const short8*)&Qb[(qbase + x) * 64 + 32 + g * 8];

  const int rp = tid >> 3, j0 = tid & 7;
  const int prow = rp * 2 + (j0 & 1);
  const int pcol = (((j0 >> 1) ^ (rp & 3)) & 3) * 8;
  const u16* srcK = Kg + (size_t)bh * 65536 + (size_t)prow * 64 + pcol;
  const u16* srcV = Vtg + (size_t)(bh * 64 + prow) * 1024 + pcol;
  const int dst0 = tid * 8;
  const int h = x >> 1, pq = x & 1;
  const int laneoff = h * 64 + (((2 * g + pq) ^ ((h & 3) << 1)) * 8);

  float mrun[4], lrun[4];
  f32x4 oacc[4];
  #pragma unroll
  for (int r = 0; r < 4; ++r) { mrun[r] = -1e30f; lrun[r] = 0.f; }
  #pragma unroll
  for (int d = 0; d < 4; ++d) oacc[d] = (f32x4){0.f, 0.f, 0.f, 0.f};

  auto stage = [&](int t) {
    u16* kd = Kb[t & 1] + dst0;
    u16* vd = Vb[t & 1] + dst0;
    const u16* ks = srcK + t * 4096;
    const u16* vs = srcV + t * 64;
    async16(ks, kd);        async16(ks + 32, kd + 2048);
    async16(vs, vd);        async16(vs + 32, vd + 2048);
  };
  stage(0);
  asm volatile("s_waitcnt vmcnt(0)\n\ts_barrier" ::: "memory");

  for (int t = 0; t <= qt; ++t) {
    const u16* kb = Kb[t & 1];
    const u16* vb = Vb[t & 1];
    if (t < qt) stage(t + 1);

    float sc[4][4];
    #pragma unroll
    for (int nb = 0; nb < 4; ++nb) {
      f32x4 a = (f32x4){0.f, 0.f, 0.f, 0.f};
      const short8 kf0 = *(const short8*)(kb + nb * 512 + laneoff);
      const short8 kf1 = *(const short8*)(kb + 2048 + nb * 512 + laneoff);
      a = mfma16(qf0, kf0, a);
      a = mfma16(qf1, kf1, a);
      #pragma unroll
      for (int r = 0; r < 4; ++r) sc[nb][r] = a[r];
    }
    if (t == qt) {
      #pragma unroll
      for (int nb = 0; nb < 4; ++nb)
        #pragma unroll
        for (int r = 0; r < 4; ++r)
          if (t * 64 + nb * 16 + x > qbase + g * 4 + r) sc[nb][r] = -1e30f;
    }
    float mnew[4], psum[4], scl[4];
    #pragma unroll
    for (int r = 0; r < 4; ++r) {
      float mx = fmaxf(fmaxf(sc[0][r], sc[1][r]), fmaxf(sc[2][r], sc[3][r]));
      mx = fmaxf(mx, DPPF(mx, 0xB1));
      mx = fmaxf(mx, DPPF(mx, 0x4E));
      mx = fmaxf(mx, DPPF(mx, 0x124));
      mx = fmaxf(mx, DPPF(mx, 0x128));
      mnew[r] = fmaxf(mrun[r], mx);
      scl[r] = __expf(mrun[r] - mnew[r]);
      mrun[r] = mnew[r];
      psum[r] = 0.f;
    }
    float p[4][4];
    #pragma unroll
    for (int nb = 0; nb < 4; ++nb)
      #pragma unroll
      for (int r = 0; r < 4; ++r) {
        p[nb][r] = __expf(sc[nb][r] - mnew[r]);
        psum[r] += p[nb][r];
      }
    #pragma unroll
    for (int r = 0; r < 4; ++r) {
      psum[r] += DPPF(psum[r], 0xB1);
      psum[r] += DPPF(psum[r], 0x4E);
      psum[r] += DPPF(psum[r], 0x124);
      psum[r] += DPPF(psum[r], 0x128);
      lrun[r] = lrun[r] * scl[r] + psum[r];
      #pragma unroll
      for (int db = 0; db < 4; ++db) oacc[db][r] *= scl[r];
    }
    u16* Pw = Pl[wave];
    #pragma unroll
    for (int nb = 0; nb < 4; ++nb) {
      const int half = nb >> 1;
      #pragma unroll
      for (int r = 0; r < 4; ++r) {
        const int qr = g * 4 + r;
        const int col5 = (nb & 1) * 16 + x;
        const int c8 = col5 >> 3, c7 = col5 & 7;
        const int rq = qr >> 1;
        const int jq = (qr & 1) | ((c8 ^ (rq & 3)) << 1);
        Pw[half * 512 + rq * 64 + jq * 8 + c7] = f2b(p[nb][r]);
      }
    }
    const short8 pf0 = *(const short8*)(Pw + laneoff);
    const short8 pf1 = *(const short8*)(Pw + 512 + laneoff);
    #pragma unroll
    for (int db = 0; db < 4; ++db) {
      const short8 vf0 = *(const short8*)(vb + db * 512 + laneoff);
      const short8 vf1 = *(const short8*)(vb + 2048 + db * 512 + laneoff);
      oacc[db] = mfma16(pf0, vf0, oacc[db]);
      oacc[db] = mfma16(pf1, vf1, oacc[db]);
    }
    if (t < qt)
      asm volatile("s_waitcnt vmcnt(0)\n\ts_barrier" ::: "memory");
  }
  const int b = bh >> 4, hh = bh & 15;
  #pragma unroll
  for (int db = 0; db < 4; ++db)
    #pragma unroll
    for (int r = 0; r < 4; ++r) {
      const int qrow = qbase + g * 4 + r;
      O[((size_t)(b * 1024 + qrow)) * 1024 + hh * 64 + db * 16 + x] = f2b(oacc[db][r] / lrun[r]);
    }
}

// ---------------------------------------------------------------------- launch
extern "C" void kernel_launch(void* const* d_in, const int* in_sizes, int n_in,
                              void* d_out, int out_size, void* d_ws, size_t ws_size,
                              hipStream_t stream) {
  const float* x    = (const float*)d_in[0];
  const float* ln1w = (const float*)d_in[1];
  const float* ln1b = (const float*)d_in[2];
  const float* wip  = (const float*)d_in[3];
  const float* bip  = (const float*)d_in[4];
  const float* wop  = (const float*)d_in[5];
  const float* bop  = (const float*)d_in[6];
  const float* ln2w = (const float*)d_in[7];
  const float* ln2b = (const float*)d_in[8];
  const float* muw  = (const float*)d_in[9];
  const float* sgw  = (const float*)d_in[10];
  const float* gate = (const float*)d_in[11];
  const float* mub  = (const float*)d_in[12];
  const float* wf2  = (const float*)d_in[13];
  const float* bf2  = (const float*)d_in[14];

  float* out_x = (float*)d_out;
  float* out_scores = out_x + (size_t)8192 * 1024;
  float* out_masked = out_scores + (size_t)8192 * 4096;

  char* ws = (char*)d_ws;
  size_t off = 0;
  auto alloc = [&](size_t n) { char* p = ws + off; off += (n + 255) & ~(size_t)255; return p; };
  u16* h_bf    = (u16*)alloc((size_t)8192 * 1024 * 2);
  u16* q_bf    = (u16*)alloc((size_t)8192 * 1024 * 2);
  u16* k_bf    = (u16*)alloc((size_t)8192 * 1024 * 2);
  u16* v_bf    = (u16*)alloc((size_t)8192 * 1024 * 2);
  u16* vt_bf   = (u16*)alloc((size_t)8192 * 1024 * 2);
  u16* o_bf    = (u16*)alloc((size_t)8192 * 1024 * 2);
  float* x_res = (float*)alloc((size_t)8192 * 1024 * 4);
  u16* xr_bf   = (u16*)alloc((size_t)8192 * 1024 * 2);
  float* xn    = (float*)alloc((size_t)8192 * 4);
  float* kn    = (float*)alloc((size_t)4096 * 4);
  u16* wcat    = (u16*)alloc((size_t)8192 * 1024 * 2);
  u16* wip_b   = (u16*)alloc((size_t)3072 * 1024 * 2);
  u16* wop_b   = (u16*)alloc((size_t)1024 * 1024 * 2);
  u16* wf2_b   = (u16*)alloc((size_t)1024 * 4096 * 2);
  u16* act_bf  = (u16*)alloc((size_t)8192 * 4096 * 2);

  f2bf_multi<<<2048, 256, 0, stream>>>(wip, wop, wf2, wip_b);
  prep_keys<<<4096, 256, 0, stream>>>(muw, sgw, wcat, kn);
  ln4_kernel<<<2048, 256, 0, stream>>>(x, ln1w, ln1b, h_bf, nullptr);
  gemm_bt<0, 128><<<768, 512, 0, stream>>>(h_bf, wip_b, 8192, 3072, 1024,
      bip, nullptr, nullptr, q_bf, k_bf, v_bf);
  vtrans<<<dim3(16, 128), 256, 0, stream>>>(v_bf, vt_bf);
  attn_kernel<<<dim3(128, 16), 256, 0, stream>>>(q_bf, k_bf, vt_bf, o_bf);
  gemm_bt<1, 128><<<256, 512, 0, stream>>>(o_bf, wop_b, 8192, 1024, 1024,
      bop, x, x_res, nullptr, nullptr, nullptr);
  ln4_kernel<<<2048, 256, 0, stream>>>(x_res, ln2w, ln2b, xr_bf, xn);
  moie_gemm<<<1024, 512, 0, stream>>>(xr_bf, wcat, xn, kn, mub, gate,
      out_scores, out_masked, act_bf);
  gemm_bt<3, 128><<<256, 512, 0, stream>>>(act_bf, wf2_b, 8192, 1024, 4096,
      bf2, x_res, out_x, nullptr, nullptr, nullptr);
}

// Round 18
// 491.087 us; speedup vs baseline: 1.0572x; 1.0203x over previous
//
#include <hip/hip_runtime.h>

typedef unsigned short u16;
typedef unsigned int u32;
typedef unsigned long long u64;
typedef __attribute__((ext_vector_type(8))) short short8;
typedef __attribute__((ext_vector_type(4))) float f32x4;

#define DEV static __device__ __forceinline__

// DPP lane-permute within 16-lane rows (pure VALU, no LDS pipe)
#define DPPF(v, c) __int_as_float(__builtin_amdgcn_mov_dpp(__float_as_int(v), (c), 0xf, 0xf, true))

DEV u16 f2b(float f) {
  union { float f; u32 u; } a; a.f = f;
  u32 r = a.u + 0x7fffu + ((a.u >> 16) & 1u);
  return (u16)(r >> 16);
}

DEV f32x4 mfma16(short8 a, short8 b, f32x4 c) {
  return __builtin_amdgcn_mfma_f32_16x16x32_bf16(a, b, c, 0, 0, 0);
}

DEV void async16(const void* g, void* l) {
  __builtin_amdgcn_global_load_lds(
      (const __attribute__((address_space(1))) u32*)g,
      (__attribute__((address_space(3))) u32*)l, 16, 0, 0);
}

// ---------- fused prologue: region-split over blockIdx.x (all independent)
//   blocks 0..2047    : f2bf of wip|wop|wf2 -> contiguous bf16 dst
//   blocks 2048..6143 : prep_keys (keys=mu*softplus(sigma), kn_inv)
//   blocks 6144..8191 : layernorm1 (4 rows/block, wave-per-row, no xn)
__global__ __launch_bounds__(256) void prologue_k(
    const float* __restrict__ s0, const float* __restrict__ s1f,
    const float* __restrict__ s2, u16* __restrict__ wdst,
    const float* __restrict__ mu, const float* __restrict__ sg,
    u16* __restrict__ wcat, float* __restrict__ kn,
    const float* __restrict__ x, const float* __restrict__ lw,
    const float* __restrict__ lb, u16* __restrict__ y) {
  __shared__ float sred[4];
  const int bid = (int)blockIdx.x;
  const int tid = threadIdx.x, lane = tid & 63, wave = tid >> 6;
  if (bid < 2048) {
    const int stride = 2048 * 256;
    for (int i = bid * 256 + tid; i < 2097152; i += stride) {
      f32x4 v;
      if (i < 786432) v = ((const f32x4*)s0)[i];
      else if (i < 1048576) v = ((const f32x4*)s1f)[i - 786432];
      else v = ((const f32x4*)s2)[i - 1048576];
      union { u64 q; u16 s[4]; } pk;
      pk.s[0] = f2b(v[0]); pk.s[1] = f2b(v[1]); pk.s[2] = f2b(v[2]); pk.s[3] = f2b(v[3]);
      ((u64*)wdst)[i] = pk.q;
    }
  } else if (bid < 6144) {
    const int row = bid - 2048;
    const f32x4 m = *(const f32x4*)(mu + (size_t)row * 1024 + tid * 4);
    const f32x4 s = *(const f32x4*)(sg + (size_t)row * 1024 + tid * 4);
    float q = 0.f;
    union { u64 q; u16 s[4]; } pkk, pkm;
    #pragma unroll
    for (int j = 0; j < 4; ++j) {
      const float sp = (s[j] > 20.f) ? s[j] : log1pf(__expf(s[j]));
      const float k = m[j] * sp;
      q += k * k;
      pkk.s[j] = f2b(k);
      pkm.s[j] = f2b(m[j]);
    }
    *(u64*)(wcat + (size_t)row * 1024 + tid * 4) = pkk.q;
    *(u64*)(wcat + (size_t)(4096 + row) * 1024 + tid * 4) = pkm.q;
    #pragma unroll
    for (int d = 1; d < 64; d <<= 1) q += __shfl_xor(q, d);
    if (lane == 0) sred[wave] = q;
    __syncthreads();
    if (tid == 0) kn[row] = 1.0f / fmaxf(sqrtf(sred[0] + sred[1] + sred[2] + sred[3]), 1e-8f);
  } else {
    const int row = (bid - 6144) * 4 + wave;
    const float* xr = x + (size_t)row * 1024;
    f32x4 xv[4];
    float s = 0.f, q = 0.f;
    #pragma unroll
    for (int j = 0; j < 4; ++j) {
      xv[j] = *(const f32x4*)(xr + j * 256 + lane * 4);
      #pragma unroll
      for (int u = 0; u < 4; ++u) { s += xv[j][u]; q += xv[j][u] * xv[j][u]; }
    }
    #pragma unroll
    for (int d = 1; d < 64; d <<= 1) { s += __shfl_xor(s, d); q += __shfl_xor(q, d); }
    const float mean = s * (1.f / 1024.f);
    const float inv = rsqrtf(q * (1.f / 1024.f) - mean * mean + 1e-5f);
    #pragma unroll
    for (int j = 0; j < 4; ++j) {
      const f32x4 wv = *(const f32x4*)(lw + j * 256 + lane * 4);
      const f32x4 bv = *(const f32x4*)(lb + j * 256 + lane * 4);
      union { u64 q; u16 s[4]; } pk;
      #pragma unroll
      for (int u = 0; u < 4; ++u)
        pk.s[u] = f2b((xv[j][u] - mean) * inv * wv[u] + bv[u]);
      *(u64*)(y + (size_t)row * 1024 + j * 256 + lane * 4) = pk.q;
    }
  }
}

// --------------- layernorm, wave-per-row (4 rows/block, no LDS, no barriers)
__global__ __launch_bounds__(256) void ln4_kernel(
    const float* __restrict__ x, const float* __restrict__ w,
    const float* __restrict__ b, u16* __restrict__ y, float* __restrict__ xn) {
  const int tid = threadIdx.x, lane = tid & 63, wave = tid >> 6;
  const int row = blockIdx.x * 4 + wave;
  const float* xr = x + (size_t)row * 1024;
  f32x4 xv[4];
  float s = 0.f, q = 0.f;
  #pragma unroll
  for (int j = 0; j < 4; ++j) {
    xv[j] = *(const f32x4*)(xr + j * 256 + lane * 4);
    #pragma unroll
    for (int u = 0; u < 4; ++u) { s += xv[j][u]; q += xv[j][u] * xv[j][u]; }
  }
  #pragma unroll
  for (int d = 1; d < 64; d <<= 1) { s += __shfl_xor(s, d); q += __shfl_xor(q, d); }
  const float mean = s * (1.f / 1024.f);
  const float inv = rsqrtf(q * (1.f / 1024.f) - mean * mean + 1e-5f);
  float qs = 0.f;
  #pragma unroll
  for (int j = 0; j < 4; ++j) {
    const f32x4 wv = *(const f32x4*)(w + j * 256 + lane * 4);
    const f32x4 bv = *(const f32x4*)(b + j * 256 + lane * 4);
    union { u64 q; u16 s[4]; } pk;
    #pragma unroll
    for (int u = 0; u < 4; ++u) {
      const float yv = (xv[j][u] - mean) * inv * wv[u] + bv[u];
      qs += yv * yv;
      pk.s[u] = f2b(yv);
    }
    *(u64*)(y + (size_t)row * 1024 + j * 256 + lane * 4) = pk.q;
  }
  if (xn) {
    #pragma unroll
    for (int d = 1; d < 64; d <<= 1) qs += __shfl_xor(qs, d);
    if (lane == 0) xn[row] = 1.0f / fmaxf(sqrtf(qs), 1e-8f);
  }
}

// ---------------------- GEMM C = A[M,K] * W[N,K]^T  (round-3 proven template)
template<int MODE, int BM>
__global__ __launch_bounds__(512, 2) void gemm_bt(
    const u16* __restrict__ A, const u16* __restrict__ W,
    int M, int N, int K,
    const float* __restrict__ aux0, const float* __restrict__ aux1,
    float* __restrict__ fo0,
    u16* __restrict__ bo0, u16* __restrict__ bo1, u16* __restrict__ bo2) {
  constexpr int MF = BM / 32;
  constexpr int A_U16 = BM * 32;
  constexpr int STRIDE = A_U16 + 8192;
  constexpr int AISS = BM / 128;
  constexpr int LPT = AISS + 2;
  __shared__ __align__(16) u16 lds[3 * STRIDE];

  const int tid = threadIdx.x;
  const int lane = tid & 63, wave = tid >> 6;
  const int x = lane & 15, g = lane >> 4;
  const int wm = wave >> 2, wn = wave & 3;

  const int gx = N >> 8;
  const int nwg = gridDim.x;
  const int wg = ((int)blockIdx.x & 7) * (nwg >> 3) + ((int)blockIdx.x >> 3);
  const int by = wg / gx, bx = wg - by * gx;
  const int m0 = by * BM, n0 = bx * 256;

  const u16* srcA[AISS]; const u16* srcB[2];
  int dA[AISS], dB[2];
  #pragma unroll
  for (int i = 0; i < AISS; ++i) {
    const int rp = i * 64 + (tid >> 3);
    const int pre = (tid & 7) ^ (rp & 7);
    const int row = rp * 2 + (pre & 1), col = (pre >> 1) * 8;
    srcA[i] = A + (size_t)(m0 + row) * K + col;
    dA[i] = i * 4096 + tid * 8;
  }
  #pragma unroll
  for (int i = 0; i < 2; ++i) {
    const int rp = i * 64 + (tid >> 3);
    const int pre = (tid & 7) ^ (rp & 7);
    const int row = rp * 2 + (pre & 1), col = (pre >> 1) * 8;
    srcB[i] = W + (size_t)(n0 + row) * K + col;
    dB[i] = A_U16 + i * 4096 + tid * 8;
  }
  const int lane_off = (x >> 1) * 64 + (((2 * g + (x & 1)) ^ (x >> 1)) * 8);
  const int aoff = wm * (BM / 4) * 64 + lane_off;
  const int boff = A_U16 + wn * 2048 + lane_off;

  f32x4 acc[MF][4];
  #pragma unroll
  for (int f = 0; f < MF; ++f)
    #pragma unroll
    for (int j = 0; j < 4; ++j) acc[f][j] = (f32x4){0.f, 0.f, 0.f, 0.f};

  const int NT = K >> 5;
  auto stage = [&](int t, int b) {
    u16* buf = lds + b * STRIDE;
    const size_t ko = (size_t)t * 32;
    #pragma unroll
    for (int i = 0; i < AISS; ++i) async16(srcA[i] + ko, buf + dA[i]);
    #pragma unroll
    for (int i = 0; i < 2; ++i) async16(srcB[i] + ko, buf + dB[i]);
  };
  stage(0, 0);
  stage(1, 1);
  int br = 0, bs = 2;
  for (int t = 0; t < NT; ++t) {
    if (t < NT - 1)
      asm volatile("s_waitcnt vmcnt(%0)\n\ts_barrier" :: "n"(LPT) : "memory");
    else
      asm volatile("s_waitcnt vmcnt(0)\n\ts_barrier" ::: "memory");
    const u16* bufr = lds + br * STRIDE;
    short8 bfr[4], af[MF];
    #pragma unroll
    for (int j = 0; j < 4; ++j) bfr[j] = *(const short8*)(bufr + boff + j * 512);
    #pragma unroll
    for (int f = 0; f < MF; ++f) af[f] = *(const short8*)(bufr + aoff + f * 512);
    if (t + 2 < NT) stage(t + 2, bs);
    __builtin_amdgcn_s_setprio(1);
    #pragma unroll
    for (int f = 0; f < MF; ++f)
      #pragma unroll
      for (int j = 0; j < 4; ++j) acc[f][j] = mfma16(af[f], bfr[j], acc[f][j]);
    __builtin_amdgcn_s_setprio(0);
    br = (br == 2) ? 0 : br + 1;
    bs = (bs == 2) ? 0 : bs + 1;
  }

  const int col_base = n0 + wn * 64;
  const int row_base = m0 + wm * (BM / 2);
  #pragma unroll
  for (int f = 0; f < MF; ++f)
    #pragma unroll
    for (int j = 0; j < 4; ++j)
      #pragma unroll
      for (int r = 0; r < 4; ++r) {
        const int row = row_base + f * 16 + g * 4 + r;
        const int col = col_base + j * 16 + x;
        float v = acc[f][j][r];
        if constexpr (MODE == 0) {
          v += aux0[col];
          const int part = col >> 10, cc = col & 1023;
          const int hh = cc >> 6, dd = cc & 63;
          const size_t idx = ((size_t)((row >> 10) * 16 + hh) * 1024 + (row & 1023)) * 64 + dd;
          if (part == 0) bo0[idx] = f2b(v * 0.125f);
          else if (part == 1) bo1[idx] = f2b(v);
          else bo2[idx] = f2b(v);
        } else if constexpr (MODE == 1) {
          fo0[(size_t)row * 1024 + col] = v + aux0[col] + aux1[(size_t)row * 1024 + col];
        } else {
          // ffn2 out_x: never re-read -> non-temporal
          __builtin_nontemporal_store(
              v + aux0[col] + aux1[(size_t)row * 1024 + col],
              &fo0[(size_t)row * 1024 + col]);
        }
      }
}

// ---------------- moie GEMM v3 (round-10 best: BK=32, 4-deep buffers, depth-3
// prefetch, ONE vmcnt(8)+barrier per K-tile, register-local fused epilogue)
__global__ __launch_bounds__(512, 2) void moie_gemm(
    const u16* __restrict__ A, const u16* __restrict__ W,
    const float* __restrict__ xni, const float* __restrict__ kni,
    const float* __restrict__ mub, const float* __restrict__ gate,
    float* __restrict__ oscore, float* __restrict__ omask,
    u16* __restrict__ oact) {
  __shared__ __align__(16) u16 lds[4 * 16384];
  const int tid = threadIdx.x;
  const int lane = tid & 63, wave = tid >> 6;
  const int x = lane & 15, g = lane >> 4, h = x >> 1, pp = x & 1;
  const int wm = wave >> 2, wn = wave & 3;

  const int bid = (int)blockIdx.x;
  const int local = bid >> 3;
  const int by = (bid & 7) * 4 + (local & 3);
  const int bx = local >> 2;
  const int m0 = by * 256, n0 = bx * 128;

  const int rp0 = tid >> 3, j0 = tid & 7;
  const int prow = rp0 * 2 + (j0 & 1);
  const int pcol = (((j0 >> 1) ^ (rp0 & 3)) & 3) * 8;
  const u16* Asrc[2]; const u16* Bsrc[2];
  Asrc[0] = A + (size_t)(m0 + prow) * 1024 + pcol;
  Asrc[1] = A + (size_t)(m0 + 128 + prow) * 1024 + pcol;
  #pragma unroll
  for (int c = 0; c < 2; ++c) {
    const int rb = c * 128 + prow;
    const u16* base = (rb & 32) ? (W + (size_t)4096 * 1024) : W;
    Bsrc[c] = base + (size_t)(n0 + ((rb >> 6) << 5) + (rb & 31)) * 1024 + pcol;
  }
  const int dst0 = tid * 8;
  const int laneoff = h * 64 + (((2 * g + pp) ^ ((h & 3) << 1)) * 8);

  f32x4 acc[8][4];
  #pragma unroll
  for (int i = 0; i < 8; ++i)
    #pragma unroll
    for (int j = 0; j < 4; ++j) acc[i][j] = (f32x4){0.f, 0.f, 0.f, 0.f};

  auto stageA = [&](int t) {
    u16* dst = lds + (t & 3) * 16384 + dst0;
    const int ko = t * 32;
    async16(Asrc[0] + ko, dst);
    async16(Asrc[1] + ko, dst + 4096);
  };
  auto stageB = [&](int t) {
    u16* dst = lds + (t & 3) * 16384 + 8192 + dst0;
    const int ko = t * 32;
    async16(Bsrc[0] + ko, dst);
    async16(Bsrc[1] + ko, dst + 4096);
  };

  stageA(0); stageB(0); stageA(1); stageB(1); stageA(2); stageB(2);
  asm volatile("s_waitcnt vmcnt(8)\n\ts_barrier" ::: "memory");

  constexpr int NT = 32;
  for (int t = 0; t < NT; ++t) {
    const u16* bufA = lds + (t & 3) * 16384;
    const u16* bufB = bufA + 8192;
    short8 bf[4], af[8];
    #pragma unroll
    for (int j = 0; j < 4; ++j)
      bf[j] = *(const short8*)(bufB + wn * 2048 + j * 512 + laneoff);
    #pragma unroll
    for (int f = 0; f < 8; ++f)
      af[f] = *(const short8*)(bufA + wm * 4096 + f * 512 + laneoff);
    if (t + 3 < NT) { stageB(t + 3); stageA(t + 3); }
    __builtin_amdgcn_s_setprio(1);
    #pragma unroll
    for (int f = 0; f < 8; ++f)
      #pragma unroll
      for (int j = 0; j < 4; ++j) acc[f][j] = mfma16(af[f], bf[j], acc[f][j]);
    __builtin_amdgcn_s_setprio(0);
    if (t <= NT - 4)
      asm volatile("s_waitcnt vmcnt(8)\n\ts_barrier" ::: "memory");
    else if (t == NT - 3)
      asm volatile("s_waitcnt vmcnt(4)\n\ts_barrier" ::: "memory");
    else if (t == NT - 2)
      asm volatile("s_waitcnt vmcnt(0)\n\ts_barrier" ::: "memory");
  }

  #pragma unroll
  for (int i = 0; i < 8; ++i) {
    const int row = m0 + wm * 128 + i * 16 + g * 4;
    const f32x4 xv = *(const f32x4*)(xni + row);
    #pragma unroll
    for (int jj = 0; jj < 2; ++jj) {
      const int gcol = n0 + wn * 32 + jj * 16 + x;
      const float kv = kni[gcol], gt = gate[gcol], mb = mub[gcol];
      #pragma unroll
      for (int r = 0; r < 4; ++r) {
        const float s = acc[i][jj][r] * xv[r] * kv;
        const float comp = acc[i][jj + 2][r] + mb;
        const float mk = comp * fmaxf(s - gt, 0.f);
        oscore[(size_t)(row + r) * 4096 + gcol] = s;
        omask[(size_t)(row + r) * 4096 + gcol] = mk;
        oact[(size_t)(row + r) * 4096 + gcol] = f2b(mk / (1.f + __expf(-mk)));
      }
    }
  }
}

// ---------------------------------------- V transpose: v[bh][s][d] -> vt[bh][d][s]
__global__ __launch_bounds__(256) void vtrans(const u16* __restrict__ v,
                                              u16* __restrict__ vt) {
  __shared__ u16 tl[64 * 66];
  const int bh = blockIdx.y, s0 = blockIdx.x * 64;
  const int tid = threadIdx.x;
  const int r8 = tid >> 3, c8 = tid & 7;
  #pragma unroll
  for (int p = 0; p < 2; ++p) {
    const int row = r8 + p * 32;
    *(short8*)&tl[row * 66 + c8 * 8] =
        *(const short8*)&v[((size_t)bh * 1024 + s0 + row) * 64 + c8 * 8];
  }
  __syncthreads();
  #pragma unroll
  for (int p = 0; p < 2; ++p) {
    const int d = r8 + p * 32;
    union { short8 v; u16 s[8]; } pk;
    #pragma unroll
    for (int j = 0; j < 8; ++j) pk.s[j] = tl[(c8 * 8 + j) * 66 + d];
    *(short8*)&vt[((size_t)bh * 64 + d) * 1024 + s0 + c8 * 8] = pk.v;
  }
}

// ------------------- flash attention v3 + LPT: heaviest q-tiles dispatch first
__global__ __launch_bounds__(256) void attn_kernel(
    const u16* __restrict__ Q, const u16* __restrict__ Kg,
    const u16* __restrict__ Vtg, u16* __restrict__ O) {
  __shared__ __align__(16) u16 Kb[2][4096];
  __shared__ __align__(16) u16 Vb[2][4096];
  __shared__ __align__(16) u16 Pl[4][1024];
  const int bh = blockIdx.x;
  const int qt = 15 - (int)blockIdx.y;   // LPT: heavy blocks (qt=15) first
  const int tid = threadIdx.x, lane = tid & 63, wave = tid >> 6;
  const int x = lane & 15, g = lane >> 4;
  const u16* Qb = Q + (size_t)bh * 1024 * 64;
  const int qbase = qt * 64 + wave * 16;
  const short8 qf0 = *(const short8*)&Qb[(qbase + x) * 64 + g * 8];
  const short8 qf1 = *(const short8*)&Qb[(qbase + x) * 64 + 32 + g * 8];

  const int rp = tid >> 3, j0 = tid & 7;
  const int prow = rp * 2 + (j0 & 1);
  const int pcol = (((j0 >> 1) ^ (rp & 3)) & 3) * 8;
  const u16* srcK = Kg + (size_t)bh * 65536 + (size_t)prow * 64 + pcol;
  const u16* srcV = Vtg + (size_t)(bh * 64 + prow) * 1024 + pcol;
  const int dst0 = tid * 8;
  const int h = x >> 1, pq = x & 1;
  const int laneoff = h * 64 + (((2 * g + pq) ^ ((h & 3) << 1)) * 8);

  float mrun[4], lrun[4];
  f32x4 oacc[4];
  #pragma unroll
  for (int r = 0; r < 4; ++r) { mrun[r] = -1e30f; lrun[r] = 0.f; }
  #pragma unroll
  for (int d = 0; d < 4; ++d) oacc[d] = (f32x4){0.f, 0.f, 0.f, 0.f};

  auto stage = [&](int t) {
    u16* kd = Kb[t & 1] + dst0;
    u16* vd = Vb[t & 1] + dst0;
    const u16* ks = srcK + t * 4096;
    const u16* vs = srcV + t * 64;
    async16(ks, kd);        async16(ks + 32, kd + 2048);
    async16(vs, vd);        async16(vs + 32, vd + 2048);
  };
  stage(0);
  asm volatile("s_waitcnt vmcnt(0)\n\ts_barrier" ::: "memory");

  for (int t = 0; t <= qt; ++t) {
    const u16* kb = Kb[t & 1];
    const u16* vb = Vb[t & 1];
    if (t < qt) stage(t + 1);

    float sc[4][4];
    #pragma unroll
    for (int nb = 0; nb < 4; ++nb) {
      f32x4 a = (f32x4){0.f, 0.f, 0.f, 0.f};
      const short8 kf0 = *(const short8*)(kb + nb * 512 + laneoff);
      const short8 kf1 = *(const short8*)(kb + 2048 + nb * 512 + laneoff);
      a = mfma16(qf0, kf0, a);
      a = mfma16(qf1, kf1, a);
      #pragma unroll
      for (int r = 0; r < 4; ++r) sc[nb][r] = a[r];
    }
    if (t == qt) {
      #pragma unroll
      for (int nb = 0; nb < 4; ++nb)
        #pragma unroll
        for (int r = 0; r < 4; ++r)
          if (t * 64 + nb * 16 + x > qbase + g * 4 + r) sc[nb][r] = -1e30f;
    }
    float mnew[4], psum[4], scl[4];
    #pragma unroll
    for (int r = 0; r < 4; ++r) {
      float mx = fmaxf(fmaxf(sc[0][r], sc[1][r]), fmaxf(sc[2][r], sc[3][r]));
      mx = fmaxf(mx, DPPF(mx, 0xB1));
      mx = fmaxf(mx, DPPF(mx, 0x4E));
      mx = fmaxf(mx, DPPF(mx, 0x124));
      mx = fmaxf(mx, DPPF(mx, 0x128));
      mnew[r] = fmaxf(mrun[r], mx);
      scl[r] = __expf(mrun[r] - mnew[r]);
      mrun[r] = mnew[r];
      psum[r] = 0.f;
    }
    float p[4][4];
    #pragma unroll
    for (int nb = 0; nb < 4; ++nb)
      #pragma unroll
      for (int r = 0; r < 4; ++r) {
        p[nb][r] = __expf(sc[nb][r] - mnew[r]);
        psum[r] += p[nb][r];
      }
    #pragma unroll
    for (int r = 0; r < 4; ++r) {
      psum[r] += DPPF(psum[r], 0xB1);
      psum[r] += DPPF(psum[r], 0x4E);
      psum[r] += DPPF(psum[r], 0x124);
      psum[r] += DPPF(psum[r], 0x128);
      lrun[r] = lrun[r] * scl[r] + psum[r];
      #pragma unroll
      for (int db = 0; db < 4; ++db) oacc[db][r] *= scl[r];
    }
    u16* Pw = Pl[wave];
    #pragma unroll
    for (int nb = 0; nb < 4; ++nb) {
      const int half = nb >> 1;
      #pragma unroll
      for (int r = 0; r < 4; ++r) {
        const int qr = g * 4 + r;
        const int col5 = (nb & 1) * 16 + x;
        const int c8 = col5 >> 3, c7 = col5 & 7;
        const int rq = qr >> 1;
        const int jq = (qr & 1) | ((c8 ^ (rq & 3)) << 1);
        Pw[half * 512 + rq * 64 + jq * 8 + c7] = f2b(p[nb][r]);
      }
    }
    const short8 pf0 = *(const short8*)(Pw + laneoff);
    const short8 pf1 = *(const short8*)(Pw + 512 + laneoff);
    #pragma unroll
    for (int db = 0; db < 4; ++db) {
      const short8 vf0 = *(const short8*)(vb + db * 512 + laneoff);
      const short8 vf1 = *(const short8*)(vb + 2048 + db * 512 + laneoff);
      oacc[db] = mfma16(pf0, vf0, oacc[db]);
      oacc[db] = mfma16(pf1, vf1, oacc[db]);
    }
    if (t < qt)
      asm volatile("s_waitcnt vmcnt(0)\n\ts_barrier" ::: "memory");
  }
  const int b = bh >> 4, hh = bh & 15;
  #pragma unroll
  for (int db = 0; db < 4; ++db)
    #pragma unroll
    for (int r = 0; r < 4; ++r) {
      const int qrow = qbase + g * 4 + r;
      O[((size_t)(b * 1024 + qrow)) * 1024 + hh * 64 + db * 16 + x] = f2b(oacc[db][r] / lrun[r]);
    }
}

// ---------------------------------------------------------------------- launch
extern "C" void kernel_launch(void* const* d_in, const int* in_sizes, int n_in,
                              void* d_out, int out_size, void* d_ws, size_t ws_size,
                              hipStream_t stream) {
  const float* x    = (const float*)d_in[0];
  const float* ln1w = (const float*)d_in[1];
  const float* ln1b = (const float*)d_in[2];
  const float* wip  = (const float*)d_in[3];
  const float* bip  = (const float*)d_in[4];
  const float* wop  = (const float*)d_in[5];
  const float* bop  = (const float*)d_in[6];
  const float* ln2w = (const float*)d_in[7];
  const float* ln2b = (const float*)d_in[8];
  const float* muw  = (const float*)d_in[9];
  const float* sgw  = (const float*)d_in[10];
  const float* gate = (const float*)d_in[11];
  const float* mub  = (const float*)d_in[12];
  const float* wf2  = (const float*)d_in[13];
  const float* bf2  = (const float*)d_in[14];

  float* out_x = (float*)d_out;
  float* out_scores = out_x + (size_t)8192 * 1024;
  float* out_masked = out_scores + (size_t)8192 * 4096;

  char* ws = (char*)d_ws;
  size_t off = 0;
  auto alloc = [&](size_t n) { char* p = ws + off; off += (n + 255) & ~(size_t)255; return p; };
  u16* h_bf    = (u16*)alloc((size_t)8192 * 1024 * 2);
  u16* q_bf    = (u16*)alloc((size_t)8192 * 1024 * 2);
  u16* k_bf    = (u16*)alloc((size_t)8192 * 1024 * 2);
  u16* v_bf    = (u16*)alloc((size_t)8192 * 1024 * 2);
  u16* vt_bf   = (u16*)alloc((size_t)8192 * 1024 * 2);
  u16* o_bf    = (u16*)alloc((size_t)8192 * 1024 * 2);
  float* x_res = (float*)alloc((size_t)8192 * 1024 * 4);
  u16* xr_bf   = (u16*)alloc((size_t)8192 * 1024 * 2);
  float* xn    = (float*)alloc((size_t)8192 * 4);
  float* kn    = (float*)alloc((size_t)4096 * 4);
  u16* wcat    = (u16*)alloc((size_t)8192 * 1024 * 2);
  u16* wip_b   = (u16*)alloc((size_t)3072 * 1024 * 2);
  u16* wop_b   = (u16*)alloc((size_t)1024 * 1024 * 2);
  u16* wf2_b   = (u16*)alloc((size_t)1024 * 4096 * 2);
  u16* act_bf  = (u16*)alloc((size_t)8192 * 4096 * 2);

  prologue_k<<<8192, 256, 0, stream>>>(wip, wop, wf2, wip_b,
      muw, sgw, wcat, kn, x, ln1w, ln1b, h_bf);
  gemm_bt<0, 128><<<768, 512, 0, stream>>>(h_bf, wip_b, 8192, 3072, 1024,
      bip, nullptr, nullptr, q_bf, k_bf, v_bf);
  vtrans<<<dim3(16, 128), 256, 0, stream>>>(v_bf, vt_bf);
  attn_kernel<<<dim3(128, 16), 256, 0, stream>>>(q_bf, k_bf, vt_bf, o_bf);
  gemm_bt<1, 128><<<256, 512, 0, stream>>>(o_bf, wop_b, 8192, 1024, 1024,
      bop, x, x_res, nullptr, nullptr, nullptr);
  ln4_kernel<<<2048, 256, 0, stream>>>(x_res, ln2w, ln2b, xr_bf, xn);
  moie_gemm<<<1024, 512, 0, stream>>>(xr_bf, wcat, xn, kn, mub, gate,
      out_scores, out_masked, act_bf);
  gemm_bt<3, 128><<<256, 512, 0, stream>>>(act_bf, wf2_b, 8192, 1024, 4096,
      bf2, x_res, out_x, nullptr, nullptr, nullptr);
}